// Round 1
// baseline (501.954 us; speedup 1.0000x reference)
//
#include <hip/hip_runtime.h>
#include <stdint.h>

// Problem constants
#define BB 2
#define SS 4096
#define EE 512
#define HH 8
#define DD 64
#define BH 16          // BB*HH
#define M_ROWS 8192    // BB*SS
#define N_COLS 1536    // 3*EE
#define K_DIM 512      // EE

typedef unsigned short u16;
typedef unsigned int u32;
typedef __attribute__((ext_vector_type(8))) __bf16 bf16x8;
typedef __attribute__((ext_vector_type(4))) float f32x4;

__device__ __forceinline__ u16 f2bf(float f) {
  u32 u = __float_as_uint(f);
  u32 r = u + 0x7fffu + ((u >> 16) & 1u);   // RNE
  return (u16)(r >> 16);
}

// ---------------- fp32 -> bf16 convert (vectorized, grid-stride) ----------------
__global__ __launch_bounds__(256) void cvt_f32_bf16(const float* __restrict__ src,
                                                    u16* __restrict__ dst, int n) {
  int stride = gridDim.x * blockDim.x * 4;
  for (int i = (blockIdx.x * blockDim.x + threadIdx.x) * 4; i < n; i += stride) {
    float4 v = *(const float4*)(src + i);
    u32 lo = (u32)f2bf(v.x) | ((u32)f2bf(v.y) << 16);
    u32 hi = (u32)f2bf(v.z) | ((u32)f2bf(v.w) << 16);
    uint2 p; p.x = lo; p.y = hi;
    *(uint2*)(dst + i) = p;
  }
}

// ---------------- QKV GEMM: C[m][n] = sum_k X[m][k] * W[n][k] ----------------
// 128x128 tile, BK=64, 4 waves (each 64x64), 16x16x32 bf16 MFMA.
// Epilogue scatters into Q (scaled by 1/sqrt(D)), K, V in [b][h][s][d] bf16.
#define BM 128
#define BN 128
#define BK 64

__global__ __launch_bounds__(256) void qkv_gemm(const u16* __restrict__ Xb,
                                                const u16* __restrict__ Wb,
                                                u16* __restrict__ Qg,
                                                u16* __restrict__ Kg,
                                                u16* __restrict__ Vg) {
  __shared__ u16 Al[BM * BK];   // rows of 128B, XOR-swizzled
  __shared__ u16 Bl[BN * BK];

  const int tid = threadIdx.x;
  const int lane = tid & 63;
  const int w = tid >> 6;
  const int wr = w >> 1, wc = w & 1;
  const int m0 = blockIdx.x * BM;
  const int n0 = blockIdx.y * BN;

  f32x4 acc[4][4] = {};
  uint4 ra[4], rb[4];

  auto loadT = [&](int kt) {
#pragma unroll
    for (int i = 0; i < 4; i++) {
      int c = i * 256 + tid;           // 0..1023 chunk id (16B chunks)
      int row = c >> 3, seg = c & 7;
      ra[i] = *(const uint4*)(Xb + (size_t)(m0 + row) * K_DIM + kt * BK + seg * 8);
      rb[i] = *(const uint4*)(Wb + (size_t)(n0 + row) * K_DIM + kt * BK + seg * 8);
    }
  };
  auto storeT = [&]() {
#pragma unroll
    for (int i = 0; i < 4; i++) {
      int c = i * 256 + tid;
      int row = c >> 3, seg = c & 7;
      int byte = row * 128 + ((seg * 16) ^ ((row & 7) << 4));
      *(uint4*)((char*)Al + byte) = ra[i];
      *(uint4*)((char*)Bl + byte) = rb[i];
    }
  };

  loadT(0);
  const int NKT = K_DIM / BK;   // 8
  for (int kt = 0; kt < NKT; ++kt) {
    __syncthreads();            // previous tile's reads done
    storeT();
    __syncthreads();            // tile visible
    if (kt + 1 < NKT) loadT(kt + 1);   // prefetch next (overlaps MFMA below)

#pragma unroll
    for (int ks = 0; ks < 2; ++ks) {
      bf16x8 af[4], bfr[4];
#pragma unroll
      for (int t = 0; t < 4; t++) {
        int row = wr * 64 + t * 16 + (lane & 15);
        int byte = row * 128 + (((ks * 64) + (lane >> 4) * 16) ^ ((row & 7) << 4));
        af[t] = *(const bf16x8*)((const char*)Al + byte);
      }
#pragma unroll
      for (int t = 0; t < 4; t++) {
        int row = wc * 64 + t * 16 + (lane & 15);
        int byte = row * 128 + (((ks * 64) + (lane >> 4) * 16) ^ ((row & 7) << 4));
        bfr[t] = *(const bf16x8*)((const char*)Bl + byte);
      }
#pragma unroll
      for (int am = 0; am < 4; am++)
#pragma unroll
        for (int bn = 0; bn < 4; bn++)
          acc[am][bn] = __builtin_amdgcn_mfma_f32_16x16x32_bf16(af[am], bfr[bn], acc[am][bn], 0, 0, 0);
    }
  }

  // Epilogue: C layout col = lane&15, row = (lane>>4)*4 + i  [m89-verified]
  const float scale = 0.125f;   // 1/sqrt(64)
#pragma unroll
  for (int am = 0; am < 4; am++) {
    int mbase = m0 + wr * 64 + am * 16 + (lane >> 4) * 4;
#pragma unroll
    for (int bn = 0; bn < 4; bn++) {
      int n = n0 + wc * 64 + bn * 16 + (lane & 15);
      int which = n >> 9;            // 0=q 1=k 2=v
      int hh = (n >> 6) & 7, dd = n & 63;
#pragma unroll
      for (int i = 0; i < 4; i++) {
        int m = mbase + i;
        int b = m >> 12, s = m & 4095;
        size_t off = ((size_t)(b * HH + hh) * SS + s) * DD + dd;
        float v = acc[am][bn][i];
        if (which == 0)      Qg[off] = f2bf(v * scale);
        else if (which == 1) Kg[off] = f2bf(v);
        else                 Vg[off] = f2bf(v);
      }
    }
  }
}

// ---------------- V transpose per head: [s][d] -> [d][s] ----------------
__global__ __launch_bounds__(256) void transpose_v(const u16* __restrict__ Vg,
                                                   u16* __restrict__ Vt) {
  __shared__ u16 t[64][80];     // +16 elem pad
  int bh = blockIdx.y, s0 = blockIdx.x * 64;
  int tid = threadIdx.x;
#pragma unroll
  for (int i = 0; i < 2; i++) {
    int c = i * 256 + tid;
    int row = c >> 3, seg = c & 7;
    *(uint4*)&t[row][seg * 8] =
        *(const uint4*)(Vg + ((size_t)bh * SS + s0 + row) * DD + seg * 8);
  }
  __syncthreads();
#pragma unroll
  for (int i = 0; i < 2; i++) {
    int c = i * 256 + tid;
    int d = c >> 3, seg = c & 7;
    u16 tmp[8];
#pragma unroll
    for (int j = 0; j < 8; j++) tmp[j] = t[seg * 8 + j][d];
    *(uint4*)(Vt + ((size_t)bh * DD + d) * SS + s0 + seg * 8) = *(uint4*)tmp;
  }
}

// ---------------- Flash attention ----------------
// grid: (S/64, B*H). 4 waves/block; wave w owns q rows [qt*64+w*16, +16).
// K tile and V^T tile staged in swizzled LDS; P transits per-wave swizzled LDS.
#define KBLK 64
#define NT (SS / KBLK)   // 64

__global__ __launch_bounds__(256) void flash_attn(const u16* __restrict__ Qg,
                                                  const u16* __restrict__ Kg,
                                                  const u16* __restrict__ Vt,
                                                  float* __restrict__ Out) {
  __shared__ u16 Kl[KBLK * 64];     // [key][d], swizzled 128B rows
  __shared__ u16 Vl[64 * KBLK];     // [d][key], swizzled
  __shared__ u16 Pl[4][16 * 64];    // per-wave P [q][key], swizzled

  const int tid = threadIdx.x;
  const int lane = tid & 63;
  const int w = tid >> 6;
  const int bh = blockIdx.y;
  const int q0 = blockIdx.x * 64 + w * 16;

  // Q fragments (A-layout: row = lane&15, k = (lane>>4)*8 + j), scale pre-folded
  bf16x8 qf[2];
  {
    const u16* qp = Qg + ((size_t)bh * SS + q0 + (lane & 15)) * DD + (lane >> 4) * 8;
    qf[0] = *(const bf16x8*)qp;
    qf[1] = *(const bf16x8*)(qp + 32);
  }

  f32x4 o[4] = {};                  // o[nb][i]: row q=(lane>>4)*4+i, col d=nb*16+(lane&15)
  float mrun[4], lrun[4];
#pragma unroll
  for (int i = 0; i < 4; i++) { mrun[i] = -1e30f; lrun[i] = 0.f; }

  uint4 rk[2], rv[2];
  auto loadKV = [&](int kt) {
#pragma unroll
    for (int i = 0; i < 2; i++) {
      int c = i * 256 + tid;
      int row = c >> 3, seg = c & 7;
      rk[i] = *(const uint4*)(Kg + ((size_t)bh * SS + kt * KBLK + row) * DD + seg * 8);
      rv[i] = *(const uint4*)(Vt + ((size_t)bh * DD + row) * SS + kt * KBLK + seg * 8);
    }
  };
  auto storeKV = [&]() {
#pragma unroll
    for (int i = 0; i < 2; i++) {
      int c = i * 256 + tid;
      int row = c >> 3, seg = c & 7;
      int byte = row * 128 + ((seg * 16) ^ ((row & 7) << 4));
      *(uint4*)((char*)Kl + byte) = rk[i];
      *(uint4*)((char*)Vl + byte) = rv[i];
    }
  };

  loadKV(0);
  for (int kt = 0; kt < NT; ++kt) {
    __syncthreads();
    storeKV();
    __syncthreads();
    if (kt + 1 < NT) loadKV(kt + 1);   // prefetch next KV tile into regs

    // ---- QK^T : S[q][key], A=Q frag, B=K^T frag (reads K rows, d-contiguous)
    f32x4 sf[4];
#pragma unroll
    for (int nb = 0; nb < 4; nb++) {
      f32x4 z = {};
#pragma unroll
      for (int ks = 0; ks < 2; ks++) {
        int row = nb * 16 + (lane & 15);
        int byte = row * 128 + (((ks * 64) + (lane >> 4) * 16) ^ ((row & 7) << 4));
        bf16x8 kf = *(const bf16x8*)((const char*)Kl + byte);
        z = __builtin_amdgcn_mfma_f32_16x16x32_bf16(qf[ks], kf, z, 0, 0, 0);
      }
      sf[nb] = z;
    }

    // ---- online softmax (wave-parallel, 16-lane-group shuffle reduce)
    float p[4][4], alpha[4];
#pragma unroll
    for (int i = 0; i < 4; i++) {
      float tm = fmaxf(fmaxf(sf[0][i], sf[1][i]), fmaxf(sf[2][i], sf[3][i]));
#pragma unroll
      for (int off = 8; off >= 1; off >>= 1) tm = fmaxf(tm, __shfl_xor(tm, off, 64));
      float mnew = fmaxf(mrun[i], tm);
      alpha[i] = __expf(mrun[i] - mnew);
      mrun[i] = mnew;
      float rs = 0.f;
#pragma unroll
      for (int nb = 0; nb < 4; nb++) {
        float e = __expf(sf[nb][i] - mnew);
        p[nb][i] = e;
        rs += e;
      }
#pragma unroll
      for (int off = 8; off >= 1; off >>= 1) rs += __shfl_xor(rs, off, 64);
      lrun[i] = lrun[i] * alpha[i] + rs;
#pragma unroll
      for (int nb = 0; nb < 4; nb++) o[nb][i] *= alpha[i];
    }

    // ---- P -> bf16 -> per-wave LDS (swizzled), then PV
    u16* pw = Pl[w];
#pragma unroll
    for (int nb = 0; nb < 4; nb++)
#pragma unroll
      for (int i = 0; i < 4; i++) {
        int q = (lane >> 4) * 4 + i;
        int key = nb * 16 + (lane & 15);
        int byte = q * 128 + ((key * 2) ^ ((q & 7) << 4));
        *(u16*)((char*)pw + byte) = f2bf(p[nb][i]);
      }

#pragma unroll
    for (int ks = 0; ks < 2; ks++) {
      int qrow = lane & 15;
      int pbyte = qrow * 128 + (((ks * 64) + (lane >> 4) * 16) ^ ((qrow & 7) << 4));
      bf16x8 pf = *(const bf16x8*)((const char*)pw + pbyte);
#pragma unroll
      for (int nb = 0; nb < 4; nb++) {
        int drow = nb * 16 + (lane & 15);
        int vbyte = drow * 128 + (((ks * 64) + (lane >> 4) * 16) ^ ((drow & 7) << 4));
        bf16x8 vf = *(const bf16x8*)((const char*)Vl + vbyte);
        o[nb] = __builtin_amdgcn_mfma_f32_16x16x32_bf16(pf, vf, o[nb], 0, 0, 0);
      }
    }
  }

  // ---- epilogue: out[b][s][h*64+d] = o / l
  int b = bh >> 3, hh = bh & 7;
#pragma unroll
  for (int nb = 0; nb < 4; nb++) {
    int dd = nb * 16 + (lane & 15);
#pragma unroll
    for (int i = 0; i < 4; i++) {
      int q = q0 + (lane >> 4) * 4 + i;
      Out[((size_t)b * SS + q) * EE + hh * DD + dd] = o[nb][i] / lrun[i];
    }
  }
}

// ---------------- launch ----------------
extern "C" void kernel_launch(void* const* d_in, const int* in_sizes, int n_in,
                              void* d_out, int out_size, void* d_ws, size_t ws_size,
                              hipStream_t stream) {
  const float* x = (const float*)d_in[0];
  const float* Wq = (const float*)d_in[1];
  // segment_len / dilation unused: dilation==1, world_size==1 -> plain SDPA

  u16* xb = (u16*)d_ws;                              // [8192][512] bf16
  u16* wb = xb + (size_t)M_ROWS * K_DIM;             // [1536][512]
  u16* Qg = wb + (size_t)N_COLS * K_DIM;             // [16][4096][64] (scaled)
  u16* Kg = Qg + (size_t)BH * SS * DD;
  u16* Vg = Kg + (size_t)BH * SS * DD;
  u16* Vt = Vg + (size_t)BH * SS * DD;               // [16][64][4096]

  cvt_f32_bf16<<<2048, 256, 0, stream>>>(x, xb, M_ROWS * K_DIM);
  cvt_f32_bf16<<<768, 256, 0, stream>>>(Wq, wb, N_COLS * K_DIM);

  dim3 g1(M_ROWS / BM, N_COLS / BN);   // 64 x 12
  qkv_gemm<<<g1, 256, 0, stream>>>(xb, wb, Qg, Kg, Vg);

  dim3 g2(SS / 64, BH);
  transpose_v<<<g2, 256, 0, stream>>>(Vg, Vt);

  dim3 g3(SS / 64, BH);
  flash_attn<<<g3, 256, 0, stream>>>(Qg, Kg, Vt, (float*)d_out);
}

// Round 2
// 288.046 us; speedup vs baseline: 1.7426x; 1.7426x over previous
//
#include <hip/hip_runtime.h>
#include <stdint.h>

// Problem constants
#define BB 2
#define SS 4096
#define EE 512
#define HH 8
#define DD 64
#define BH 16          // BB*HH
#define M_ROWS 8192    // BB*SS
#define N_COLS 1536    // 3*EE
#define K_DIM 512      // EE

typedef unsigned short u16;
typedef unsigned int u32;
typedef __attribute__((ext_vector_type(8))) __bf16 bf16x8;
typedef __attribute__((ext_vector_type(4))) float f32x4;
typedef __attribute__((ext_vector_type(16))) float f32x16;

__device__ __forceinline__ u16 f2bf(float f) {
  u32 u = __float_as_uint(f);
  u32 r = u + 0x7fffu + ((u >> 16) & 1u);   // RNE
  return (u16)(r >> 16);
}

__device__ __forceinline__ u32 cvtpk(float a, float b) {
  u32 r;
  asm("v_cvt_pk_bf16_f32 %0, %1, %2" : "=v"(r) : "v"(a), "v"(b));
  return r;
}

// ---------------- fp32 -> bf16 convert (vectorized, grid-stride) ----------------
__global__ __launch_bounds__(256) void cvt_f32_bf16(const float* __restrict__ src,
                                                    u16* __restrict__ dst, int n) {
  int stride = gridDim.x * blockDim.x * 4;
  for (int i = (blockIdx.x * blockDim.x + threadIdx.x) * 4; i < n; i += stride) {
    float4 v = *(const float4*)(src + i);
    u32 lo = (u32)f2bf(v.x) | ((u32)f2bf(v.y) << 16);
    u32 hi = (u32)f2bf(v.z) | ((u32)f2bf(v.w) << 16);
    uint2 p; p.x = lo; p.y = hi;
    *(uint2*)(dst + i) = p;
  }
}

// ---------------- QKV GEMM: C[m][n] = sum_k X[m][k] * W[n][k] ----------------
// 128x128 tile, BK=64, 4 waves (each 64x64), 16x16x32 bf16 MFMA.
// Epilogue: Q scaled by 1/8 -> [bh][s][d]; K -> [bh][s][d]; V -> TRANSPOSED [bh][d][s].
#define BM 128
#define BN 128
#define BK 64

__global__ __launch_bounds__(256) void qkv_gemm(const u16* __restrict__ Xb,
                                                const u16* __restrict__ Wb,
                                                u16* __restrict__ Qg,
                                                u16* __restrict__ Kg,
                                                u16* __restrict__ Vt) {
  __shared__ u16 Al[BM * BK];   // rows of 128B, XOR-swizzled
  __shared__ u16 Bl[BN * BK];

  const int tid = threadIdx.x;
  const int lane = tid & 63;
  const int w = tid >> 6;
  const int wr = w >> 1, wc = w & 1;
  const int m0 = blockIdx.x * BM;
  const int n0 = blockIdx.y * BN;

  f32x4 acc[4][4] = {};
  uint4 ra[4], rb[4];

  auto loadT = [&](int kt) {
#pragma unroll
    for (int i = 0; i < 4; i++) {
      int c = i * 256 + tid;           // 16B chunks
      int row = c >> 3, seg = c & 7;
      ra[i] = *(const uint4*)(Xb + (size_t)(m0 + row) * K_DIM + kt * BK + seg * 8);
      rb[i] = *(const uint4*)(Wb + (size_t)(n0 + row) * K_DIM + kt * BK + seg * 8);
    }
  };
  auto storeT = [&]() {
#pragma unroll
    for (int i = 0; i < 4; i++) {
      int c = i * 256 + tid;
      int row = c >> 3, seg = c & 7;
      int byte = row * 128 + ((seg * 16) ^ ((row & 7) << 4));
      *(uint4*)((char*)Al + byte) = ra[i];
      *(uint4*)((char*)Bl + byte) = rb[i];
    }
  };

  loadT(0);
  const int NKT = K_DIM / BK;   // 8
  for (int kt = 0; kt < NKT; ++kt) {
    __syncthreads();
    storeT();
    __syncthreads();
    if (kt + 1 < NKT) loadT(kt + 1);

#pragma unroll
    for (int ks = 0; ks < 2; ++ks) {
      bf16x8 af[4], bfr[4];
#pragma unroll
      for (int t = 0; t < 4; t++) {
        int row = wr * 64 + t * 16 + (lane & 15);
        int byte = row * 128 + (((ks * 64) + (lane >> 4) * 16) ^ ((row & 7) << 4));
        af[t] = *(const bf16x8*)((const char*)Al + byte);
      }
#pragma unroll
      for (int t = 0; t < 4; t++) {
        int row = wc * 64 + t * 16 + (lane & 15);
        int byte = row * 128 + (((ks * 64) + (lane >> 4) * 16) ^ ((row & 7) << 4));
        bfr[t] = *(const bf16x8*)((const char*)Bl + byte);
      }
#pragma unroll
      for (int am = 0; am < 4; am++)
#pragma unroll
        for (int bn = 0; bn < 4; bn++)
          acc[am][bn] = __builtin_amdgcn_mfma_f32_16x16x32_bf16(af[am], bfr[bn], acc[am][bn], 0, 0, 0);
    }
  }

  // Epilogue: C layout col = lane&15, row = (lane>>4)*4 + i  [m89-verified]
  const float scale = 0.125f;   // 1/sqrt(64)
#pragma unroll
  for (int am = 0; am < 4; am++) {
    int mbase = m0 + wr * 64 + am * 16 + (lane >> 4) * 4;   // multiple of 4
#pragma unroll
    for (int bn = 0; bn < 4; bn++) {
      int n = n0 + wc * 64 + bn * 16 + (lane & 15);
      int which = n >> 9;            // 0=q 1=k 2=v
      int hh = (n >> 6) & 7, dd = n & 63;
      int b = mbase >> 12;           // same for all 4 i (mbase%4==0)
      int bh = b * HH + hh;
      if (which == 2) {
        // V transposed: Vt[bh][dd][s], 4 consecutive s -> one 8B store
        union { u16 h[4]; uint2 u; } pk;
#pragma unroll
        for (int i = 0; i < 4; i++) pk.h[i] = f2bf(acc[am][bn][i]);
        *(uint2*)(Vt + ((size_t)bh * DD + dd) * SS + (mbase & 4095)) = pk.u;
      } else {
        u16* dst = (which == 0) ? Qg : Kg;
        float sc = (which == 0) ? scale : 1.0f;
#pragma unroll
        for (int i = 0; i < 4; i++) {
          int s = (mbase + i) & 4095;
          dst[((size_t)bh * SS + s) * DD + dd] = f2bf(acc[am][bn][i] * sc);
        }
      }
    }
  }
}

// ---------------- Flash attention (8-phase-lite, swapped-operand 32x32) ----------------
// grid: (S/128, B*H), 4 warps/block, warp owns 32 q rows (q = lane&31, both lane halves).
// S^T = mfma(K, Q): lane holds 32 scores of ONE q row (half keys; other half in lane^32).
// P -> bf16 in-register via cvt_pk + permlane32_swap; O^T = mfma(V^T, P^T).
#define KVB 64
#define NT (SS / KVB)   // 64

__global__ __launch_bounds__(256) void flash_attn(const u16* __restrict__ Qg,
                                                  const u16* __restrict__ Kg,
                                                  const u16* __restrict__ Vt,
                                                  float* __restrict__ Out) {
  __shared__ __align__(16) char smem[32768];   // 2 bufs x (K 8KB + V^T 8KB)

  const int tid = threadIdx.x;
  const int lane = tid & 63;
  const int w = tid >> 6;
  const int hi = lane >> 5;          // 0/1
  const int lq = lane & 31;          // q within warp tile
  const int bh = blockIdx.y;
  const int q0 = blockIdx.x * 128 + w * 32;

  // Q fragments (B-operand of 32x32x16): col=q=lane&31, k(d) = ks*16 + hi*8 + j
  bf16x8 qf[4];
  {
    const u16* qp = Qg + ((size_t)bh * SS + q0 + lq) * DD + hi * 8;
#pragma unroll
    for (int ks = 0; ks < 4; ks++) qf[ks] = *(const bf16x8*)(qp + ks * 16);
  }

  f32x16 oa0 = {}, oa1 = {};         // O^T: col=q, row d = db*32 + (r&3)+8*(r>>2)+4*hi
  float m = -1e30f, l = 0.f;

  uint4 rk[2], rv[2];
  auto loadKV = [&](int kt) {
#pragma unroll
    for (int i = 0; i < 2; i++) {
      int c = i * 256 + tid;
      int row = c >> 3, seg = c & 7;
      rk[i] = *(const uint4*)(Kg + ((size_t)bh * SS + kt * KVB + row) * DD + seg * 8);
      rv[i] = *(const uint4*)(Vt + ((size_t)bh * DD + row) * SS + kt * KVB + seg * 8);
    }
  };
  auto storeKV = [&](int buf) {
    char* kb = smem + buf * 16384;
    char* vb = kb + 8192;
#pragma unroll
    for (int i = 0; i < 2; i++) {
      int c = i * 256 + tid;
      int row = c >> 3, seg = c & 7;
      int byte = row * 128 + ((seg * 16) ^ ((row & 7) << 4));
      *(uint4*)(kb + byte) = rk[i];
      *(uint4*)(vb + byte) = rv[i];
    }
  };

  loadKV(0);
  storeKV(0);
  __syncthreads();

  for (int kt = 0; kt < NT; ++kt) {
    const int cur = kt & 1;
    const char* Kc = smem + cur * 16384;
    const char* Vc = Kc + 8192;

    if (kt + 1 < NT) loadKV(kt + 1);     // issue global loads early (T14)

    // ---- QK^T (swapped): sacc[kb] = K[kb*32..+32] x Q^T  -> S^T[key][q]
    f32x16 sa0 = {}, sa1 = {};
#pragma unroll
    for (int ks = 0; ks < 4; ks++) {
      int col = ks * 32 + hi * 16;       // byte col for d-slice ks
      int r0 = lq, r1 = 32 + lq;
      bf16x8 kf0 = *(const bf16x8*)(Kc + r0 * 128 + (col ^ ((r0 & 7) << 4)));
      bf16x8 kf1 = *(const bf16x8*)(Kc + r1 * 128 + (col ^ ((r1 & 7) << 4)));
      sa0 = __builtin_amdgcn_mfma_f32_32x32x16_bf16(kf0, qf[ks], sa0, 0, 0, 0);
      sa1 = __builtin_amdgcn_mfma_f32_32x32x16_bf16(kf1, qf[ks], sa1, 0, 0, 0);
    }

    // ---- online softmax: lane owns q=lq, 32 of 64 keys (partner lane^32 has rest)
    float tm = -1e30f;
#pragma unroll
    for (int r = 0; r < 16; r++) tm = fmaxf(tm, fmaxf(sa0[r], sa1[r]));
    tm = fmaxf(tm, __shfl_xor(tm, 32));
    if (__any(tm > m + 8.f)) {           // defer-max (T13, THR=8)
      float mnew = fmaxf(m, tm);
      float al = __expf(m - mnew);
      m = mnew;
      l *= al;
#pragma unroll
      for (int r = 0; r < 16; r++) { oa0[r] *= al; oa1[r] *= al; }
    }
    float rs = 0.f;
#pragma unroll
    for (int r = 0; r < 16; r++) {
      float p0 = __expf(sa0[r] - m);
      float p1 = __expf(sa1[r] - m);
      sa0[r] = p0; sa1[r] = p1;
      rs += p0 + p1;
    }
    rs += __shfl_xor(rs, 32);
    l += rs;

    // ---- P -> bf16 B-fragments (T12: cvt_pk + permlane32_swap)
    bf16x8 paf[4];
#pragma unroll
    for (int kb = 0; kb < 2; kb++) {
#pragma unroll
      for (int h2 = 0; h2 < 2; h2++) {
        int base = h2 * 8;
        u32 a0, b0, a1, b1;
        if (kb == 0) {
          a0 = cvtpk(sa0[base + 0], sa0[base + 1]);
          b0 = cvtpk(sa0[base + 4], sa0[base + 5]);
          a1 = cvtpk(sa0[base + 2], sa0[base + 3]);
          b1 = cvtpk(sa0[base + 6], sa0[base + 7]);
        } else {
          a0 = cvtpk(sa1[base + 0], sa1[base + 1]);
          b0 = cvtpk(sa1[base + 4], sa1[base + 5]);
          a1 = cvtpk(sa1[base + 2], sa1[base + 3]);
          b1 = cvtpk(sa1[base + 6], sa1[base + 7]);
        }
        asm("v_permlane32_swap_b32 %0, %1" : "+v"(a0), "+v"(b0));
        asm("v_permlane32_swap_b32 %0, %1" : "+v"(a1), "+v"(b1));
        union { u32 d[4]; bf16x8 v; } u;
        u.d[0] = a0; u.d[1] = a1; u.d[2] = b0; u.d[3] = b1;
        paf[kb * 2 + h2] = u.v;
      }
    }

    // ---- PV (swapped): O^T += V^T[db*32..+32][keys] x P^T[keys][q]
#pragma unroll
    for (int ks = 0; ks < 4; ks++) {
      int col = ks * 32 + hi * 16;       // byte col for key-slice ks
      int r0 = lq, r1 = 32 + lq;
      bf16x8 vf0 = *(const bf16x8*)(Vc + r0 * 128 + (col ^ ((r0 & 7) << 4)));
      bf16x8 vf1 = *(const bf16x8*)(Vc + r1 * 128 + (col ^ ((r1 & 7) << 4)));
      oa0 = __builtin_amdgcn_mfma_f32_32x32x16_bf16(vf0, paf[ks], oa0, 0, 0, 0);
      oa1 = __builtin_amdgcn_mfma_f32_32x32x16_bf16(vf1, paf[ks], oa1, 0, 0, 0);
    }

    if (kt + 1 < NT) storeKV(cur ^ 1);   // vmcnt wait lands here, after compute
    __syncthreads();                     // single barrier per tile
  }

  // ---- epilogue: O^T -> LDS (per-warp 8KB) -> coalesced float4 stores
  float* ow = (float*)(smem + w * 8192);   // [32 q][64 d] f32, swizzled
  float rl = 1.0f / l;
#pragma unroll
  for (int db = 0; db < 2; db++)
#pragma unroll
    for (int r = 0; r < 16; r++) {
      int d = db * 32 + (r & 3) + 8 * (r >> 2) + 4 * hi;
      float v = (db ? oa1[r] : oa0[r]) * rl;
      *(float*)((char*)ow + lq * 256 + ((d * 4) ^ ((lq & 7) << 4))) = v;
    }
  __syncthreads();
  const int b = bh >> 3, hh = bh & 7;
#pragma unroll
  for (int i = 0; i < 8; i++) {
    int c = i * 64 + lane;               // 512 chunks of 16B per warp
    int row = c >> 4, ch = c & 15;
    float4 v = *(const float4*)((const char*)ow + row * 256 + ((ch * 16) ^ ((row & 7) << 4)));
    *(float4*)(Out + ((size_t)b * SS + q0 + row) * EE + hh * DD + ch * 4) = v;
  }
}

// ---------------- launch ----------------
extern "C" void kernel_launch(void* const* d_in, const int* in_sizes, int n_in,
                              void* d_out, int out_size, void* d_ws, size_t ws_size,
                              hipStream_t stream) {
  const float* x = (const float*)d_in[0];
  const float* Wq = (const float*)d_in[1];

  u16* xb = (u16*)d_ws;                              // [8192][512] bf16
  u16* wb = xb + (size_t)M_ROWS * K_DIM;             // [1536][512]
  u16* Qg = wb + (size_t)N_COLS * K_DIM;             // [16][4096][64] (scaled)
  u16* Kg = Qg + (size_t)BH * SS * DD;               // [16][4096][64]
  u16* Vt = Kg + (size_t)BH * SS * DD;               // [16][64][4096] (transposed)

  cvt_f32_bf16<<<2048, 256, 0, stream>>>(x, xb, M_ROWS * K_DIM);
  cvt_f32_bf16<<<768, 256, 0, stream>>>(Wq, wb, N_COLS * K_DIM);

  dim3 g1(M_ROWS / BM, N_COLS / BN);   // 64 x 12
  qkv_gemm<<<g1, 256, 0, stream>>>(xb, wb, Qg, Kg, Vt);

  dim3 g3(SS / 128, BH);               // 32 x 16 = 512 blocks
  flash_attn<<<g3, 256, 0, stream>>>(Qg, Kg, Vt, (float*)d_out);
}